// Round 5
// baseline (165.901 us; speedup 1.0000x reference)
//
#include <hip/hip_runtime.h>

// ---------------------------------------------------------------------------
// GraphSAGE 2-layer forward, bf16 MFMA, layer0 fully fused (agg+cast+GEMM).
// Segments (rows): src0 256, src1 2560, dst0 256, dst1 2560, neg0 1280, neg1 12800
// H1 row offsets: src0@0 src1@256 dst0@2816 dst1@3072 neg0@5632 neg1@6912, tot 19712
// Layer0 A layout (virtual, K=1024): cols [0,512)=self(500+12 pad), [512,1024)=mean(500+12 pad)
// ---------------------------------------------------------------------------

typedef __attribute__((ext_vector_type(8))) short bhalf8;
typedef __attribute__((ext_vector_type(4))) float floatx4;

__device__ __forceinline__ ushort f2bf(float f) {
  uint32_t u = __float_as_uint(f);
  return (ushort)((u + 0x7fffu + ((u >> 16) & 1u)) >> 16);
}
__device__ __forceinline__ float bf2f(ushort u) {
  return __uint_as_float(((uint32_t)u) << 16);
}
__device__ __forceinline__ void gll16(const void* g, void* l) {
  __builtin_amdgcn_global_load_lds((const __attribute__((address_space(1))) void*)g,
                                   (__attribute__((address_space(3))) void*)l, 16, 0, 0);
}

// ------- W pack. Grid: 1280 blocks exact. -----------------------------------
// W0p: [kstp(32)][kg(4)][n(256)][i(8)], padded-k: k<512 -> self row k (<500),
//      k>=512 -> mean row 500+(k-512) (<500 valid), else 0.
// W1p: [kstp(16)][kg(4)][n(128)][i(8)], K=512 (self 256 | mean 256, no pad).
__global__ __launch_bounds__(256) void pack_w(const float* __restrict__ W0, const float* __restrict__ W1,
                                              ushort* __restrict__ W0p, ushort* __restrict__ W1p) {
  const int idx = blockIdx.x * 256 + threadIdx.x;
  if (idx < 262144) {
    const int i = idx & 7, n = (idx >> 3) & 255, kgv = (idx >> 11) & 3, kstp = idx >> 13;
    const int k = kstp * 32 + kgv * 8 + i;  // padded k in [0,1024)
    int srcr;
    if (k < 512) srcr = (k < 500) ? k : -1;
    else { const int k2 = k - 512; srcr = (k2 < 500) ? 500 + k2 : -1; }
    W0p[idx] = (srcr >= 0) ? f2bf(W0[srcr * 256 + n]) : (ushort)0;
  } else {
    const int j = idx - 262144;
    const int i = j & 7, n = (j >> 3) & 127, kgv = (j >> 10) & 3, kstp = j >> 12;
    const int k = kstp * 32 + kgv * 8 + i;
    W1p[j] = f2bf(W1[k * 128 + n]);
  }
}

// ------- fused layer0: H1[32-row tile] = relu([self|mean10] @ W0) -----------
// 616 blocks of 256 threads (4 waves, wave n-split). BK=32, 32 k-steps:
// ks<16 self (f32 direct), ks>=16 mean-of-10 (nontemporal f32), both reg-staged
// to bf16 LDS with kg-slot XOR swizzle. B via global_load_lds, fragment-linear.
struct FusedP {
  const float* selfp[6];
  const float* neigh[6];
  int tileEnd[6];  // cumulative 32-row tiles: {8,88,96,176,216,616}
};

__global__ __launch_bounds__(256) void fused_l0(FusedP P, const ushort* __restrict__ W0p,
                                                ushort* __restrict__ H1) {
  __shared__ ushort As[2][32 * 32];   // 2 x 2 KB
  __shared__ ushort Bs[2][256 * 32];  // 2 x 16 KB

  const int tid = threadIdx.x;
  const int wid = tid >> 6, l = tid & 63;
  const int lr = l & 15, kg = l >> 4;

  const int bt = blockIdx.x;
  int s = 0;
#pragma unroll
  for (int t = 0; t < 5; ++t) s = (bt >= P.tileEnd[t]) ? t + 1 : s;
  const int tb = s ? P.tileEnd[s - 1] : 0;
  const long lrow0 = (long)(bt - tb) * 32;  // row within segment
  const long grow0 = (long)bt * 32;         // global H1 row

  // staging item: one float4-column (4 cols) of one row
  const int irow = tid >> 3, qg = tid & 7;
  const floatx4* selfF4 = (const floatx4*)P.selfp[s] + (lrow0 + irow) * 125;
  const floatx4* meanF4 = (const floatx4*)P.neigh[s] + (lrow0 + irow) * 1250;
  const int kgw = qg >> 1;
  const int wbyte = irow * 64 + ((kgw ^ ((irow >> 1) & 3)) << 4) + ((qg & 1) << 3);

  int aoff[2], boff[4];
#pragma unroll
  for (int mi = 0; mi < 2; ++mi) {
    const int row = mi * 16 + lr;
    aoff[mi] = row * 64 + ((kg ^ ((row >> 1) & 3)) << 4);
  }
#pragma unroll
  for (int ni = 0; ni < 4; ++ni) boff[ni] = (kg * 256 + wid * 64 + ni * 16 + lr) << 4;

  floatx4 acc[2][4];
#pragma unroll
  for (int mi = 0; mi < 2; ++mi)
#pragma unroll
    for (int ni = 0; ni < 4; ++ni) acc[mi][ni] = (floatx4){0.f, 0.f, 0.f, 0.f};

  floatx4 t[10];

  auto stage_issue = [&](int ks) {
    if (ks < 16) {
      const int f4 = ks * 8 + qg;
      const int c = (f4 < 125) ? f4 : 124;
      t[0] = selfF4[c];
    } else {
      const int f4 = (ks - 16) * 8 + qg;
      const int c = (f4 < 125) ? f4 : 124;
#pragma unroll
      for (int k = 0; k < 10; ++k) t[k] = __builtin_nontemporal_load(meanF4 + (long)k * 125 + c);
    }
  };
  auto stage_B = [&](int ks, int pb) {
#pragma unroll
    for (int it = 0; it < 4; ++it) {
      const ushort* g = W0p + ((size_t)(ks * 4 + it) * 256 + tid) * 8;
      gll16(g, (char*)&Bs[pb][0] + it * 4096 + wid * 1024);
    }
  };
  auto stage_finish = [&](int ks, int pb) {
    floatx4 v;
    bool valid;
    if (ks < 16) {
      valid = (ks * 8 + qg) < 125;
      v = t[0];
    } else {
      valid = ((ks - 16) * 8 + qg) < 125;
      const floatx4 s0 = t[0] + t[1], s1 = t[2] + t[3], s2 = t[4] + t[5], s3 = t[6] + t[7],
                    s4 = t[8] + t[9];
      v = (((s0 + s1) + (s2 + s3)) + s4) * 0.1f;
    }
    if (!valid) v = (floatx4){0.f, 0.f, 0.f, 0.f};
    uint2 u;
    u.x = (uint)f2bf(v.x) | ((uint)f2bf(v.y) << 16);
    u.y = (uint)f2bf(v.z) | ((uint)f2bf(v.w) << 16);
    *(uint2*)((char*)&As[pb][0] + wbyte) = u;
  };

  // prologue: stage k-step 0 into buffer 0
  stage_issue(0);
  stage_B(0, 0);
  stage_finish(0, 0);

  for (int ks = 1; ks <= 32; ++ks) {
    __syncthreads();  // buf[ks-1] ready (drains B gll + LDS writes)
    const int pb = ks & 1, pbp = pb ^ 1;
    if (ks < 32) {
      stage_issue(ks);   // loads fly under the MFMA below
      stage_B(ks, pb);
    }
    bhalf8 af[2], bfr[4];
#pragma unroll
    for (int mi = 0; mi < 2; ++mi) af[mi] = *(const bhalf8*)((const char*)&As[pbp][0] + aoff[mi]);
#pragma unroll
    for (int ni = 0; ni < 4; ++ni) bfr[ni] = *(const bhalf8*)((const char*)&Bs[pbp][0] + boff[ni]);
#pragma unroll
    for (int mi = 0; mi < 2; ++mi)
#pragma unroll
      for (int ni = 0; ni < 4; ++ni)
        acc[mi][ni] = __builtin_amdgcn_mfma_f32_16x16x32_bf16(af[mi], bfr[ni], acc[mi][ni], 0, 0, 0);
    if (ks < 32) stage_finish(ks, pb);
  }

  // epilogue: relu + bf16 store. C/D: col = lane&15, row = (lane>>4)*4 + reg
#pragma unroll
  for (int mi = 0; mi < 2; ++mi)
#pragma unroll
    for (int ni = 0; ni < 4; ++ni) {
      const int gcol = wid * 64 + ni * 16 + lr;
#pragma unroll
      for (int r = 0; r < 4; ++r) {
        const long grow = grow0 + mi * 16 + kg * 4 + r;
        H1[grow * 256 + gcol] = f2bf(fmaxf(acc[mi][ni][r], 0.f));
      }
    }
}

// ---------------- agg1: H1 bf16 -> A2 [1792][512] bf16 (self | mean10) -------
__global__ __launch_bounds__(256) void agg1_pack(const ushort* __restrict__ H1, ushort* __restrict__ A2,
                                                 long total) {
  const long stride = (long)gridDim.x * 256;
  for (long idx = (long)blockIdx.x * 256 + threadIdx.x; idx < total; idx += stride) {
    const bool g1 = idx >= 32768, g2 = idx >= 65536;
    const long base = g2 ? 65536 : (g1 ? 32768 : 0);
    const int selfo = g2 ? 5632 : (g1 ? 2816 : 0);
    const int neigho = g2 ? 6912 : (g1 ? 3072 : 256);
    const int outo = g2 ? 512 : (g1 ? 256 : 0);
    const long li = idx - base;
    const long r = li >> 7;
    const int c = (int)(li & 127);
    const ushort4* H = (const ushort4*)H1;
    ushort4 ov;
    if (c < 64) {
      ov = H[((long)selfo + r) * 64 + c];
    } else {
      const int j = c - 64;
      float ax = 0.f, ay = 0.f, az = 0.f, aw = 0.f;
#pragma unroll
      for (int k = 0; k < 10; ++k) {
        const ushort4 v = H[((long)neigho + r * 10 + k) * 64 + j];
        ax += bf2f(v.x); ay += bf2f(v.y); az += bf2f(v.z); aw += bf2f(v.w);
      }
      ov.x = f2bf(ax * 0.1f); ov.y = f2bf(ay * 0.1f);
      ov.z = f2bf(az * 0.1f); ov.w = f2bf(aw * 0.1f);
    }
    ((ushort4*)A2)[((long)outo + r) * 128 + c] = ov;
  }
}

// ---------------- MFMA GEMM (layer1): C = relu(A @ Bpacked) ------------------
template <int BM, int BN, int MI, int NI, bool OUT_BF16>
__global__ __launch_bounds__(256) void gemm_mfma(const ushort* __restrict__ A,
                                                 const ushort* __restrict__ Bp,
                                                 void* __restrict__ Cout, int K, int Nfull) {
  __shared__ ushort As[BM * 32];
  __shared__ ushort Bs[BN * 32];

  const int tid = threadIdx.x;
  const int wid = tid >> 6, l = tid & 63;
  const int wr = wid >> 1, wc = wid & 1;
  const int lr = l & 15, kg = l >> 4;
  const long row0 = (long)blockIdx.x * BM;
  const int n0 = blockIdx.y * BN;

  int aoff[MI], boff[NI];
#pragma unroll
  for (int mi = 0; mi < MI; ++mi) {
    const int row = wr * (MI * 16) + mi * 16 + lr;
    aoff[mi] = row * 64 + ((kg ^ ((row >> 1) & 3)) << 4);
  }
#pragma unroll
  for (int ni = 0; ni < NI; ++ni) {
    const int cell = kg * BN + wc * (NI * 16) + ni * 16 + lr;
    boff[ni] = cell << 4;
  }

  floatx4 acc[MI][NI];
#pragma unroll
  for (int mi = 0; mi < MI; ++mi)
#pragma unroll
    for (int ni = 0; ni < NI; ++ni) acc[mi][ni] = (floatx4){0.f, 0.f, 0.f, 0.f};

  const int ksteps = K >> 5;
  for (int ks = 0; ks < ksteps; ++ks) {
    const int k0 = ks << 5;
    __syncthreads();
#pragma unroll
    for (int it = 0; it < (BM * 64) / 4096; ++it) {
      const int o = it * 4096 + tid * 16;
      const int row = o >> 6;
      const int sw = (o >> 4) & 3;
      const int kgs = sw ^ ((row >> 1) & 3);
      const ushort* g = A + (row0 + row) * (size_t)K + (k0 + kgs * 8);
      gll16(g, (char*)As + it * 4096 + wid * 1024);
    }
#pragma unroll
    for (int it = 0; it < (BN * 64) / 4096; ++it) {
      const int cell = it * 256 + tid;
      const int bkg = cell / BN;
      const int n = cell & (BN - 1);
      const ushort* g = Bp + ((size_t)(ks * 4 + bkg) * Nfull + (n0 + n)) * 8;
      gll16(g, (char*)Bs + it * 4096 + wid * 1024);
    }
    __syncthreads();

    bhalf8 af[MI], bf[NI];
#pragma unroll
    for (int mi = 0; mi < MI; ++mi) af[mi] = *(const bhalf8*)((const char*)As + aoff[mi]);
#pragma unroll
    for (int ni = 0; ni < NI; ++ni) bf[ni] = *(const bhalf8*)((const char*)Bs + boff[ni]);
#pragma unroll
    for (int mi = 0; mi < MI; ++mi)
#pragma unroll
      for (int ni = 0; ni < NI; ++ni)
        acc[mi][ni] = __builtin_amdgcn_mfma_f32_16x16x32_bf16(af[mi], bf[ni], acc[mi][ni], 0, 0, 0);
  }

#pragma unroll
  for (int mi = 0; mi < MI; ++mi)
#pragma unroll
    for (int ni = 0; ni < NI; ++ni) {
      const floatx4 v = acc[mi][ni];
      const int gcol = n0 + wc * (NI * 16) + ni * 16 + lr;
#pragma unroll
      for (int r = 0; r < 4; ++r) {
        const long grow = row0 + wr * (MI * 16) + mi * 16 + kg * 4 + r;
        const float x = fmaxf(v[r], 0.f);
        if (OUT_BF16)
          ((ushort*)Cout)[grow * Nfull + gcol] = f2bf(x);
        else
          ((float*)Cout)[grow * Nfull + gcol] = x;
      }
    }
}

extern "C" void kernel_launch(void* const* d_in, const int* in_sizes, int n_in,
                              void* d_out, int out_size, void* d_ws, size_t ws_size,
                              hipStream_t stream) {
  const float* xsrc0 = (const float*)d_in[0];
  const float* xdst0 = (const float*)d_in[1];
  const float* xneg0 = (const float*)d_in[2];
  const float* xsrc1 = (const float*)d_in[3];
  const float* xdst1 = (const float*)d_in[4];
  const float* xneg1 = (const float*)d_in[5];
  const float* xsrc2 = (const float*)d_in[6];
  const float* xdst2 = (const float*)d_in[7];
  const float* xneg2 = (const float*)d_in[8];
  const float* W0 = (const float*)d_in[9];
  const float* W1 = (const float*)d_in[10];
  float* out = (float*)d_out;

  // workspace (ushorts), 16B aligned:
  ushort* H1 = (ushort*)d_ws;       // 19712*256 = 5,046,272
  ushort* A2 = H1 + 5046272;        // 1792*512  =   917,504
  ushort* W0p = A2 + 917504;        // 262,144
  ushort* W1p = W0p + 262144;       // 65,536   (total ~12.5 MB)

  pack_w<<<dim3(1280), dim3(256), 0, stream>>>(W0, W1, W0p, W1p);

  // ---- fused layer0 ----
  {
    FusedP p;
    const float* selfs[6] = {xsrc0, xsrc1, xdst0, xdst1, xneg0, xneg1};
    const float* neighs[6] = {xsrc1, xsrc2, xdst1, xdst2, xneg1, xneg2};
    static const int rows[6] = {256, 2560, 256, 2560, 1280, 12800};
    int cumt = 0;
    for (int j = 0; j < 6; ++j) {
      p.selfp[j] = selfs[j];
      p.neigh[j] = neighs[j];
      cumt += rows[j] / 32;
      p.tileEnd[j] = cumt;  // {8,88,96,176,216,616}
    }
    fused_l0<<<dim3(616), dim3(256), 0, stream>>>(p, W0p, H1);
  }

  // ---- layer1 agg + pack: H1 -> A2 [1792][512] ----
  agg1_pack<<<dim3(896), dim3(256), 0, stream>>>(H1, A2, 229376);

  // ---- layer1 GEMM: [1792,512] @ [512,128] -> d_out fp32 ----
  gemm_mfma<64, 64, 2, 2, false><<<dim3(28, 2), dim3(256), 0, stream>>>(A2, W1p, out, 512, 128);
}

// Round 6
// 145.066 us; speedup vs baseline: 1.1436x; 1.1436x over previous
//
#include <hip/hip_runtime.h>

// ---------------------------------------------------------------------------
// GraphSAGE 2-layer forward, bf16 MFMA, layer0 fused as phase-split:
//   phase A: stream self+mean10 tile (32 x 1024 bf16) into LDS, no barriers
//   phase B: 32 k-steps of MFMA vs W0p staged from L2
// Segments (rows): src0 256, src1 2560, dst0 256, dst1 2560, neg0 1280, neg1 12800
// H1 row offsets: src0@0 src1@256 dst0@2816 dst1@3072 neg0@5632 neg1@6912, tot 19712
// A logical K=1024: [0,512)=self(500+12 pad), [512,1024)=mean(500+12 pad)
// ---------------------------------------------------------------------------

typedef __attribute__((ext_vector_type(8))) short bhalf8;
typedef __attribute__((ext_vector_type(4))) float floatx4;

__device__ __forceinline__ ushort f2bf(float f) {
  uint32_t u = __float_as_uint(f);
  return (ushort)((u + 0x7fffu + ((u >> 16) & 1u)) >> 16);
}
__device__ __forceinline__ float bf2f(ushort u) {
  return __uint_as_float(((uint32_t)u) << 16);
}
__device__ __forceinline__ void gll16(const void* g, void* l) {
  __builtin_amdgcn_global_load_lds((const __attribute__((address_space(1))) void*)g,
                                   (__attribute__((address_space(3))) void*)l, 16, 0, 0);
}

// ------- W pack. Grid: 1280 blocks exact. -----------------------------------
// W0p: [kstp(32)][kg(4)][n(256)][i(8)]; k<512 -> self row k (<500 valid),
//      k>=512 -> mean row 500+(k-512) (<500 valid), else 0.
// W1p: [kstp(16)][kg(4)][n(128)][i(8)], K=512.
__global__ __launch_bounds__(256) void pack_w(const float* __restrict__ W0, const float* __restrict__ W1,
                                              ushort* __restrict__ W0p, ushort* __restrict__ W1p) {
  const int idx = blockIdx.x * 256 + threadIdx.x;
  if (idx < 262144) {
    const int i = idx & 7, n = (idx >> 3) & 255, kgv = (idx >> 11) & 3, kstp = idx >> 13;
    const int k = kstp * 32 + kgv * 8 + i;
    int srcr;
    if (k < 512) srcr = (k < 500) ? k : -1;
    else { const int k2 = k - 512; srcr = (k2 < 500) ? 500 + k2 : -1; }
    W0p[idx] = (srcr >= 0) ? f2bf(W0[srcr * 256 + n]) : (ushort)0;
  } else {
    const int j = idx - 262144;
    const int i = j & 7, n = (j >> 3) & 127, kgv = (j >> 10) & 3, kstp = j >> 12;
    const int k = kstp * 32 + kgv * 8 + i;
    W1p[j] = f2bf(W1[k * 128 + n]);
  }
}

// ------- fused layer0 --------------------------------------------------------
struct FusedP {
  const float* selfp[6];
  const float* neigh[6];
  int tileEnd[6];  // cumulative 32-row tiles: {8,88,96,176,216,616}
};

__global__ __launch_bounds__(256) void fused_l0(FusedP P, const ushort* __restrict__ W0p,
                                                ushort* __restrict__ H1) {
  __shared__ ushort As[32 * 1024];  // 64 KB, 2048 B/row, 16B-slot XOR swizzle by (row&7)
  __shared__ ushort Bs[32 * 256];   // 16 KB single-buffer: [kg(4)][n(256)][8]

  const int tid = threadIdx.x;
  const int wid = tid >> 6, l = tid & 63;
  const int lr = l & 15, kg = l >> 4;

  const int bt = blockIdx.x;
  int s = 0;
#pragma unroll
  for (int t = 0; t < 5; ++t) s = (bt >= P.tileEnd[t]) ? t + 1 : s;
  const int tb = s ? P.tileEnd[s - 1] : 0;
  const long lrow0 = (long)(bt - tb) * 32;
  const long grow0 = (long)bt * 32;

  // issue first B-tile staging before phase A (latency hides under the stream)
  {
#pragma unroll
    for (int it = 0; it < 4; ++it) {
      const ushort* g = W0p + ((size_t)it * 256 + tid) * 8;
      gll16(g, (char*)Bs + it * 4096 + wid * 1024);
    }
  }

  // ---- phase A: stream self + mean-of-10 into LDS (no barriers) ----
  const int irow = tid >> 3, qg = tid & 7;
  const floatx4* selfF4 = (const floatx4*)P.selfp[s] + (lrow0 + irow) * 125;
  const floatx4* meanF4 = (const floatx4*)P.neigh[s] + (lrow0 + irow) * 1250;
  const int swz = (irow & 7) << 4;
#pragma unroll 2
  for (int i = 0; i < 16; ++i) {
    const int c = qg + 8 * i;  // float4 col, [0,128)
    const bool valid = c < 125;
    const int cc = valid ? c : 0;
    floatx4 sv = selfF4[cc];
    floatx4 t0 = meanF4[cc];
    floatx4 t1 = meanF4[cc + 125];
    floatx4 t2 = meanF4[cc + 250];
    floatx4 t3 = meanF4[cc + 375];
    floatx4 t4 = meanF4[cc + 500];
    floatx4 t5 = meanF4[cc + 625];
    floatx4 t6 = meanF4[cc + 750];
    floatx4 t7 = meanF4[cc + 875];
    floatx4 t8 = meanF4[cc + 1000];
    floatx4 t9 = meanF4[cc + 1125];
    floatx4 mv = (((t0 + t1) + (t2 + t3)) + ((t4 + t5) + (t6 + t7)) + (t8 + t9)) * 0.1f;
    if (!valid) {
      sv = (floatx4){0.f, 0.f, 0.f, 0.f};
      mv = (floatx4){0.f, 0.f, 0.f, 0.f};
    }
    uint2 us, um;
    us.x = (uint)f2bf(sv.x) | ((uint)f2bf(sv.y) << 16);
    us.y = (uint)f2bf(sv.z) | ((uint)f2bf(sv.w) << 16);
    um.x = (uint)f2bf(mv.x) | ((uint)f2bf(mv.y) << 16);
    um.y = (uint)f2bf(mv.z) | ((uint)f2bf(mv.w) << 16);
    const int sb = (irow * 2048 + c * 8) ^ swz;
    const int mb = (irow * 2048 + 1024 + c * 8) ^ swz;
    *(uint2*)((char*)As + sb) = us;
    *(uint2*)((char*)As + mb) = um;
  }

  // ---- phase B: 32 k-steps, A LDS-resident, B single-buffered from L2 ----
  floatx4 acc[2][4];
#pragma unroll
  for (int mi = 0; mi < 2; ++mi)
#pragma unroll
    for (int ni = 0; ni < 4; ++ni) acc[mi][ni] = (floatx4){0.f, 0.f, 0.f, 0.f};

  int boff[4];
#pragma unroll
  for (int ni = 0; ni < 4; ++ni) boff[ni] = (kg * 256 + wid * 64 + ni * 16 + lr) << 4;

  for (int ks = 0; ks < 32; ++ks) {
    __syncthreads();  // Bs(ks) staged (vmcnt drained); ks=0 also covers As writes
    bhalf8 af[2], bfr[4];
#pragma unroll
    for (int mi = 0; mi < 2; ++mi) {
      const int row = mi * 16 + lr;
      const int addr = (row * 2048 + ks * 64 + (kg << 4)) ^ ((row & 7) << 4);
      af[mi] = *(const bhalf8*)((const char*)As + addr);
    }
#pragma unroll
    for (int ni = 0; ni < 4; ++ni) bfr[ni] = *(const bhalf8*)((const char*)Bs + boff[ni]);
#pragma unroll
    for (int mi = 0; mi < 2; ++mi)
#pragma unroll
      for (int ni = 0; ni < 4; ++ni)
        acc[mi][ni] = __builtin_amdgcn_mfma_f32_16x16x32_bf16(af[mi], bfr[ni], acc[mi][ni], 0, 0, 0);
    __syncthreads();  // all Bs reads done
    if (ks < 31) {
#pragma unroll
      for (int it = 0; it < 4; ++it) {
        const ushort* g = W0p + ((size_t)((ks + 1) * 4 + it) * 256 + tid) * 8;
        gll16(g, (char*)Bs + it * 4096 + wid * 1024);
      }
    }
  }

  // epilogue: relu + bf16 store. C/D: col = lane&15, row = (lane>>4)*4 + reg
#pragma unroll
  for (int mi = 0; mi < 2; ++mi)
#pragma unroll
    for (int ni = 0; ni < 4; ++ni) {
      const int gcol = wid * 64 + ni * 16 + lr;
#pragma unroll
      for (int r = 0; r < 4; ++r) {
        const long grow = grow0 + mi * 16 + kg * 4 + r;
        H1[grow * 256 + gcol] = f2bf(fmaxf(acc[mi][ni][r], 0.f));
      }
    }
}

// ---------------- agg1: H1 bf16 -> A2 [1792][512] bf16 (self | mean10) -------
__global__ __launch_bounds__(256) void agg1_pack(const ushort* __restrict__ H1, ushort* __restrict__ A2,
                                                 long total) {
  const long stride = (long)gridDim.x * 256;
  for (long idx = (long)blockIdx.x * 256 + threadIdx.x; idx < total; idx += stride) {
    const bool g1 = idx >= 32768, g2 = idx >= 65536;
    const long base = g2 ? 65536 : (g1 ? 32768 : 0);
    const int selfo = g2 ? 5632 : (g1 ? 2816 : 0);
    const int neigho = g2 ? 6912 : (g1 ? 3072 : 256);
    const int outo = g2 ? 512 : (g1 ? 256 : 0);
    const long li = idx - base;
    const long r = li >> 7;
    const int c = (int)(li & 127);
    const ushort4* H = (const ushort4*)H1;
    ushort4 ov;
    if (c < 64) {
      ov = H[((long)selfo + r) * 64 + c];
    } else {
      const int j = c - 64;
      float ax = 0.f, ay = 0.f, az = 0.f, aw = 0.f;
#pragma unroll
      for (int k = 0; k < 10; ++k) {
        const ushort4 v = H[((long)neigho + r * 10 + k) * 64 + j];
        ax += bf2f(v.x); ay += bf2f(v.y); az += bf2f(v.z); aw += bf2f(v.w);
      }
      ov.x = f2bf(ax * 0.1f); ov.y = f2bf(ay * 0.1f);
      ov.z = f2bf(az * 0.1f); ov.w = f2bf(aw * 0.1f);
    }
    ((ushort4*)A2)[((long)outo + r) * 128 + c] = ov;
  }
}

// ---------------- MFMA GEMM (layer1): C = relu(A @ Bpacked) ------------------
template <int BM, int BN, int MI, int NI, bool OUT_BF16>
__global__ __launch_bounds__(256) void gemm_mfma(const ushort* __restrict__ A,
                                                 const ushort* __restrict__ Bp,
                                                 void* __restrict__ Cout, int K, int Nfull) {
  __shared__ ushort As[BM * 32];
  __shared__ ushort Bs[BN * 32];

  const int tid = threadIdx.x;
  const int wid = tid >> 6, l = tid & 63;
  const int wr = wid >> 1, wc = wid & 1;
  const int lr = l & 15, kg = l >> 4;
  const long row0 = (long)blockIdx.x * BM;
  const int n0 = blockIdx.y * BN;

  int aoff[MI], boff[NI];
#pragma unroll
  for (int mi = 0; mi < MI; ++mi) {
    const int row = wr * (MI * 16) + mi * 16 + lr;
    aoff[mi] = row * 64 + ((kg ^ ((row >> 1) & 3)) << 4);
  }
#pragma unroll
  for (int ni = 0; ni < NI; ++ni) {
    const int cell = kg * BN + wc * (NI * 16) + ni * 16 + lr;
    boff[ni] = cell << 4;
  }

  floatx4 acc[MI][NI];
#pragma unroll
  for (int mi = 0; mi < MI; ++mi)
#pragma unroll
    for (int ni = 0; ni < NI; ++ni) acc[mi][ni] = (floatx4){0.f, 0.f, 0.f, 0.f};

  const int ksteps = K >> 5;
  for (int ks = 0; ks < ksteps; ++ks) {
    const int k0 = ks << 5;
    __syncthreads();
#pragma unroll
    for (int it = 0; it < (BM * 64) / 4096; ++it) {
      const int o = it * 4096 + tid * 16;
      const int row = o >> 6;
      const int sw = (o >> 4) & 3;
      const int kgs = sw ^ ((row >> 1) & 3);
      const ushort* g = A + (row0 + row) * (size_t)K + (k0 + kgs * 8);
      gll16(g, (char*)As + it * 4096 + wid * 1024);
    }
#pragma unroll
    for (int it = 0; it < (BN * 64) / 4096; ++it) {
      const int cell = it * 256 + tid;
      const int bkg = cell / BN;
      const int n = cell & (BN - 1);
      const ushort* g = Bp + ((size_t)(ks * 4 + bkg) * Nfull + (n0 + n)) * 8;
      gll16(g, (char*)Bs + it * 4096 + wid * 1024);
    }
    __syncthreads();

    bhalf8 af[MI], bf[NI];
#pragma unroll
    for (int mi = 0; mi < MI; ++mi) af[mi] = *(const bhalf8*)((const char*)As + aoff[mi]);
#pragma unroll
    for (int ni = 0; ni < NI; ++ni) bf[ni] = *(const bhalf8*)((const char*)Bs + boff[ni]);
#pragma unroll
    for (int mi = 0; mi < MI; ++mi)
#pragma unroll
      for (int ni = 0; ni < NI; ++ni)
        acc[mi][ni] = __builtin_amdgcn_mfma_f32_16x16x32_bf16(af[mi], bf[ni], acc[mi][ni], 0, 0, 0);
  }

#pragma unroll
  for (int mi = 0; mi < MI; ++mi)
#pragma unroll
    for (int ni = 0; ni < NI; ++ni) {
      const floatx4 v = acc[mi][ni];
      const int gcol = n0 + wc * (NI * 16) + ni * 16 + lr;
#pragma unroll
      for (int r = 0; r < 4; ++r) {
        const long grow = row0 + wr * (MI * 16) + mi * 16 + kg * 4 + r;
        const float x = fmaxf(v[r], 0.f);
        if (OUT_BF16)
          ((ushort*)Cout)[grow * Nfull + gcol] = f2bf(x);
        else
          ((float*)Cout)[grow * Nfull + gcol] = x;
      }
    }
}

extern "C" void kernel_launch(void* const* d_in, const int* in_sizes, int n_in,
                              void* d_out, int out_size, void* d_ws, size_t ws_size,
                              hipStream_t stream) {
  const float* xsrc0 = (const float*)d_in[0];
  const float* xdst0 = (const float*)d_in[1];
  const float* xneg0 = (const float*)d_in[2];
  const float* xsrc1 = (const float*)d_in[3];
  const float* xdst1 = (const float*)d_in[4];
  const float* xneg1 = (const float*)d_in[5];
  const float* xsrc2 = (const float*)d_in[6];
  const float* xdst2 = (const float*)d_in[7];
  const float* xneg2 = (const float*)d_in[8];
  const float* W0 = (const float*)d_in[9];
  const float* W1 = (const float*)d_in[10];
  float* out = (float*)d_out;

  // workspace (ushorts), 16B aligned:
  ushort* H1 = (ushort*)d_ws;       // 19712*256 = 5,046,272
  ushort* A2 = H1 + 5046272;        // 1792*512  =   917,504
  ushort* W0p = A2 + 917504;        // 262,144
  ushort* W1p = W0p + 262144;       // 65,536   (total ~12.5 MB)

  pack_w<<<dim3(1280), dim3(256), 0, stream>>>(W0, W1, W0p, W1p);

  // ---- fused layer0 ----
  {
    FusedP p;
    const float* selfs[6] = {xsrc0, xsrc1, xdst0, xdst1, xneg0, xneg1};
    const float* neighs[6] = {xsrc1, xsrc2, xdst1, xdst2, xneg1, xneg2};
    static const int rows[6] = {256, 2560, 256, 2560, 1280, 12800};
    int cumt = 0;
    for (int j = 0; j < 6; ++j) {
      p.selfp[j] = selfs[j];
      p.neigh[j] = neighs[j];
      cumt += rows[j] / 32;
      p.tileEnd[j] = cumt;  // {8,88,96,176,216,616}
    }
    fused_l0<<<dim3(616), dim3(256), 0, stream>>>(p, W0p, H1);
  }

  // ---- layer1 agg + pack: H1 -> A2 [1792][512] ----
  agg1_pack<<<dim3(896), dim3(256), 0, stream>>>(H1, A2, 229376);

  // ---- layer1 GEMM: [1792,512] @ [512,128] -> d_out fp32 ----
  gemm_mfma<64, 64, 2, 2, false><<<dim3(28, 2), dim3(256), 0, stream>>>(A2, W1p, out, 512, 128);
}